// Round 18
// baseline (179.920 us; speedup 1.0000x reference)
//
#include <hip/hip_runtime.h>

#define T_TOK 2048
#define HID   2048
#define NH    16
#define NKV   2
#define HD    128
#define QDIM  (NH * HD)                 // 2048
#define KVDIM (NKV * HD)                // 256
#define QKVDIM (QDIM + 2 * KVDIM)       // 2560

typedef float          f32x4  __attribute__((ext_vector_type(4)));
typedef unsigned short u16x8  __attribute__((ext_vector_type(8)));
typedef __bf16         bf16x8 __attribute__((ext_vector_type(8)));

__device__ __forceinline__ unsigned short f2bf(float f) {
    __bf16 h = (__bf16)f;
    return __builtin_bit_cast(unsigned short, h);
}

__device__ __forceinline__ f32x4 mfma16(u16x8 a, u16x8 b, f32x4 c) {
    return __builtin_amdgcn_mfma_f32_16x16x32_bf16(
        __builtin_bit_cast(bf16x8, a), __builtin_bit_cast(bf16x8, b), c, 0, 0, 0);
}

#define QSCL 0.12751743f        // 128^-0.5 * log2(e)
#define DEFER_THR 11.5416f      // defer-max threshold (log2 units)

// Split-K schedule for 128-row q-tiles (tau' 0..15), LPT order, 24/head.
// Tiles 0..7 whole (SLT=255); tiles 8..15 two chunks of <=16 k-blocks.
__device__ const unsigned char S2_TAU[24] = {
  7, 8, 9,10,11,12,13,14,15,15, 14, 6, 13, 5, 12, 4, 11, 3, 10, 2,  9, 1,  8, 0 };
__device__ const unsigned char S2_CST[24] = {
  0, 0, 0, 0, 0, 0, 0, 0, 0,16, 16, 0, 16, 0, 16, 0, 16, 0, 16, 0, 16, 0, 16, 0 };
__device__ const unsigned char S2_CNT[24] = {
 16,16,16,16,16,16,16,16,16,16, 14,14, 12,12, 10,10,  8, 8,  6, 6,  4, 4,  2, 2 };
__device__ const unsigned char S2_SLT[24] = {
 255, 0, 2, 4, 6, 8,10,12,14,15, 13,255, 11,255,  9,255,  7,255,  5,255,  3,255,  1,255 };

// ---------------------------------------------------------------------------
// K0: fp32->bf16 packs (blocks 0..6655) + RoPE cos/sin table (6656..7167).
// ---------------------------------------------------------------------------
__global__ __launch_bounds__(256) void pack_bf16_all(
    const float* __restrict__ hidden, const float* __restrict__ Wq,
    const float* __restrict__ Wk, const float* __restrict__ Wv,
    const float* __restrict__ Wo, const int* __restrict__ positions,
    unsigned short* __restrict__ hb, unsigned short* __restrict__ Wf,
    unsigned short* __restrict__ Wob, float* __restrict__ ctab)
{
    const int b = blockIdx.x;
    if (b >= 6656) {
        const int bb = b - 6656;                 // 0..511
        const int t  = bb * 4 + (threadIdx.x >> 6);
        const int j  = threadIdx.x & 63;
        float invf = expf(-(float)j * 0.14391156831212787f);  // 10000^(-j/64)
        float f = (float)positions[t] * invf;
        ctab[(size_t)t * 128 + j]      = cosf(f);
        ctab[(size_t)t * 128 + 64 + j] = sinf(f);
        return;
    }
    const float* src; unsigned short* dst; size_t off;
    if      (b < 2048) { src = hidden; dst = hb;            off = (size_t)b * 2048; }
    else if (b < 4096) { src = Wq;     dst = Wf;            off = (size_t)(b - 2048) * 2048; }
    else if (b < 4352) { src = Wk;     dst = Wf + 4194304;  off = (size_t)(b - 4096) * 2048; }
    else if (b < 4608) { src = Wv;     dst = Wf + 4718592;  off = (size_t)(b - 4352) * 2048; }
    else               { src = Wo;     dst = Wob;           off = (size_t)(b - 4608) * 2048; }

    const size_t i = off + threadIdx.x * 8;
    float4 f0 = *reinterpret_cast<const float4*>(src + i);
    float4 f1 = *reinterpret_cast<const float4*>(src + i + 4);
    u16x8 o;
    o[0]=f2bf(f0.x); o[1]=f2bf(f0.y); o[2]=f2bf(f0.z); o[3]=f2bf(f0.w);
    o[4]=f2bf(f1.x); o[5]=f2bf(f1.y); o[6]=f2bf(f1.z); o[7]=f2bf(f1.w);
    *reinterpret_cast<u16x8*>(dst + i) = o;
}

// ---------------------------------------------------------------------------
// K1a: fused QKV GEMM (round-17 verbatim). 64x128 tile, BK=64, 2-deep
// global_load_lds + vmcnt(6), XCD rectangle remap (8m x 10n per XCD).
// Epilogue fuses RoPE (q pre-scaled by QSCL) and V-transpose.
// ---------------------------------------------------------------------------
__global__ __launch_bounds__(256) void qkv_gemm_fused(
    const unsigned short* __restrict__ A,   // hb  bf16 [2048][2048]
    const unsigned short* __restrict__ B,   // Wf  bf16 [2560][2048]
    const float* __restrict__ ctab,         // [T][128] cos|sin
    unsigned short* __restrict__ qr,        // bf16 [T][QDIM], pre-scaled
    unsigned short* __restrict__ kr,        // bf16 [T][KVDIM]
    unsigned short* __restrict__ vt)        // bf16 [KVDIM][T]
{
    __shared__ alignas(16) char smem[49152];
    unsigned short* AsBase = (unsigned short*)smem;           // [2][4096]
    unsigned short* BsBase = (unsigned short*)(smem + 16384); // [2][8192]

    const int tid  = threadIdx.x;
    const int lane = tid & 63;
    const int w    = tid >> 6;
    const int lg   = lane >> 4, lc = lane & 15;

    const int x  = blockIdx.x & 7;
    const int l  = blockIdx.x >> 3;          // 0..79
    const int mt = (x >> 1) * 8 + l / 10;    // 0..31
    const int nt = (x & 1) * 10 + l % 10;    // 0..19
    const int m0 = mt * 64, n0 = nt * 128;

    const int rowL = lane >> 3;
    const int gS   = (lane & 7) ^ rowL;
    const int wr   = (w >> 1) * 32, wc = (w & 1) * 64;

    f32x4 acc[2][4] = {};

    auto stage = [&](int buf, int kb) {
        #pragma unroll
        for (int ci = 0; ci < 2; ci++) {
            const int chunk = w * 2 + ci;
            const int row   = chunk * 8 + rowL;
            const unsigned short* gpA = &A[(size_t)(m0 + row) * HID + kb + gS * 8];
            __builtin_amdgcn_global_load_lds(
                (const __attribute__((address_space(1))) void*)gpA,
                (__attribute__((address_space(3))) void*)(&AsBase[buf * 4096 + chunk * 512]),
                16, 0, 0);
        }
        #pragma unroll
        for (int ci = 0; ci < 4; ci++) {
            const int chunk = w * 4 + ci;
            const int row   = chunk * 8 + rowL;
            const unsigned short* gpB = &B[(size_t)(n0 + row) * HID + kb + gS * 8];
            __builtin_amdgcn_global_load_lds(
                (const __attribute__((address_space(1))) void*)gpB,
                (__attribute__((address_space(3))) void*)(&BsBase[buf * 8192 + chunk * 512]),
                16, 0, 0);
        }
    };

    stage(0, 0);
    const int nk = HID >> 6;
    for (int t = 0; t < nk; ++t) {
        if (t + 1 < nk) {
            stage((t + 1) & 1, (t + 1) * 64);
            asm volatile("s_waitcnt vmcnt(6)" ::: "memory");
        } else {
            asm volatile("s_waitcnt vmcnt(0)" ::: "memory");
        }
        __syncthreads();

        const unsigned short* As_ = &AsBase[(t & 1) * 4096];
        const unsigned short* Bs_ = &BsBase[(t & 1) * 8192];
        #pragma unroll
        for (int kk = 0; kk < 2; kk++) {
            u16x8 af[2], bf[4];
            const int g = (kk * 4 + lg) ^ (lc & 7);
            #pragma unroll
            for (int mi = 0; mi < 2; mi++) {
                const int r = wr + mi * 16 + lc;
                af[mi] = *reinterpret_cast<const u16x8*>(&As_[r * 64 + g * 8]);
            }
            #pragma unroll
            for (int ni = 0; ni < 4; ni++) {
                const int r = wc + ni * 16 + lc;
                bf[ni] = *reinterpret_cast<const u16x8*>(&Bs_[r * 64 + g * 8]);
            }
            #pragma unroll
            for (int mi = 0; mi < 2; mi++)
                #pragma unroll
                for (int ni = 0; ni < 4; ni++)
                    acc[mi][ni] = mfma16(af[mi], bf[ni], acc[mi][ni]);
        }
        __syncthreads();
    }

    // ------------------ fused epilogue ------------------
    if (n0 < QDIM + KVDIM) {
        float* Ep = (float*)smem;                        // 64 x 132 f32
        #pragma unroll
        for (int mi = 0; mi < 2; mi++)
            #pragma unroll
            for (int ni = 0; ni < 4; ni++)
                #pragma unroll
                for (int j = 0; j < 4; j++)
                    Ep[(wr + mi * 16 + lg * 4 + j) * 132 + wc + ni * 16 + lc]
                        = acc[mi][ni][j];
        __syncthreads();

        const bool isq = (n0 < QDIM);
        const float scl = isq ? QSCL : 1.0f;
        unsigned short* dst  = isq ? qr : kr;
        const int rowstride  = isq ? QDIM : KVDIM;
        const int colbase    = isq ? n0 : (n0 - QDIM);

        const int r  = tid >> 2;
        const int jb = (tid & 3) * 16;
        const float* ct = ctab + (size_t)(m0 + r) * 128;
        unsigned short* drow = dst + (size_t)(m0 + r) * rowstride + colbase;
        #pragma unroll
        for (int g = 0; g < 4; g++) {
            ushort4 p1, p2;
            #pragma unroll
            for (int e = 0; e < 4; e++) {
                const int j = jb + g * 4 + e;
                float x1 = Ep[r * 132 + j];
                float x2 = Ep[r * 132 + j + 64];
                float c = ct[j], s = ct[64 + j];
                ((unsigned short*)&p1)[e] = f2bf((x1 * c - x2 * s) * scl);
                ((unsigned short*)&p2)[e] = f2bf((x2 * c + x1 * s) * scl);
            }
            *reinterpret_cast<ushort4*>(drow + jb + g * 4)      = p1;
            *reinterpret_cast<ushort4*>(drow + jb + g * 4 + 64) = p2;
        }
    } else {
        #pragma unroll
        for (int mi = 0; mi < 2; mi++)
            #pragma unroll
            for (int ni = 0; ni < 4; ni++) {
                const int d   = (n0 - QDIM - KVDIM) + wc + ni * 16 + lc;
                const int t0r = m0 + wr + mi * 16 + lg * 4;
                ushort4 pk;
                pk.x = f2bf(acc[mi][ni][0]);
                pk.y = f2bf(acc[mi][ni][1]);
                pk.z = f2bf(acc[mi][ni][2]);
                pk.w = f2bf(acc[mi][ni][3]);
                *reinterpret_cast<ushort4*>(&vt[(size_t)d * T_TOK + t0r]) = pk;
            }
    }
}

// ---------------------------------------------------------------------------
// K1b: out-proj GEMM (round-17 verbatim). 64x128 tile, 3-deep pipelined
// global_load_lds (vmcnt(12)), XCD rectangle remap (8m x 8n per XCD).
// ---------------------------------------------------------------------------
__global__ __launch_bounds__(256) void gemm_out(
    const unsigned short* __restrict__ A,   // att bf16 [T][QDIM]
    const unsigned short* __restrict__ B,   // Wob bf16 [HID][QDIM]
    float* __restrict__ C)                  // fp32 [T][HID]
{
    __shared__ alignas(16) unsigned short As[3][64 * 64];
    __shared__ alignas(16) unsigned short Bs[3][128 * 64];

    const int tid  = threadIdx.x;
    const int lane = tid & 63;
    const int w    = tid >> 6;
    const int lg   = lane >> 4, lc = lane & 15;

    const int x  = blockIdx.x & 7;
    const int l  = blockIdx.x >> 3;          // 0..63
    const int mt = (x >> 1) * 8 + (l >> 3);  // 0..31
    const int nt = (x & 1) * 8 + (l & 7);    // 0..15
    const int m0 = mt * 64, n0 = nt * 128;

    const int rowL = lane >> 3;
    const int gS   = (lane & 7) ^ rowL;
    const int wr   = (w >> 1) * 32, wc = (w & 1) * 64;

    f32x4 acc[2][4] = {};

    auto stage = [&](int buf, int kb) {
        #pragma unroll
        for (int ci = 0; ci < 2; ci++) {
            const int chunk = w * 2 + ci;
            const int row   = chunk * 8 + rowL;
            const unsigned short* gpA = &A[(size_t)(m0 + row) * QDIM + kb + gS * 8];
            __builtin_amdgcn_global_load_lds(
                (const __attribute__((address_space(1))) void*)gpA,
                (__attribute__((address_space(3))) void*)(&As[buf][chunk * 512]),
                16, 0, 0);
        }
        #pragma unroll
        for (int ci = 0; ci < 4; ci++) {
            const int chunk = w * 4 + ci;
            const int row   = chunk * 8 + rowL;
            const unsigned short* gpB = &B[(size_t)(n0 + row) * QDIM + kb + gS * 8];
            __builtin_amdgcn_global_load_lds(
                (const __attribute__((address_space(1))) void*)gpB,
                (__attribute__((address_space(3))) void*)(&Bs[buf][chunk * 512]),
                16, 0, 0);
        }
    };

    stage(0, 0);
    stage(1, 64);
    const int nk = QDIM >> 6;                // 32
    int buf = 0;
    for (int t = 0; t < nk; ++t) {
        if (t + 2 < nk) {
            stage((t + 2) % 3, (t + 2) * 64);
            asm volatile("s_waitcnt vmcnt(12)" ::: "memory");
        } else if (t + 1 < nk) {
            asm volatile("s_waitcnt vmcnt(6)" ::: "memory");
        } else {
            asm volatile("s_waitcnt vmcnt(0)" ::: "memory");
        }
        __syncthreads();

        const unsigned short* As_ = As[buf];
        const unsigned short* Bs_ = Bs[buf];
        #pragma unroll
        for (int kk = 0; kk < 2; kk++) {
            u16x8 af[2], bf[4];
            const int g = (kk * 4 + lg) ^ (lc & 7);
            #pragma unroll
            for (int mi = 0; mi < 2; mi++) {
                const int r = wr + mi * 16 + lc;
                af[mi] = *reinterpret_cast<const u16x8*>(&As_[r * 64 + g * 8]);
            }
            #pragma unroll
            for (int ni = 0; ni < 4; ni++) {
                const int r = wc + ni * 16 + lc;
                bf[ni] = *reinterpret_cast<const u16x8*>(&Bs_[r * 64 + g * 8]);
            }
            #pragma unroll
            for (int mi = 0; mi < 2; mi++)
                #pragma unroll
                for (int ni = 0; ni < 4; ni++)
                    acc[mi][ni] = mfma16(af[mi], bf[ni], acc[mi][ni]);
        }
        __syncthreads();
        buf = (buf == 2) ? 0 : buf + 1;
    }

    #pragma unroll
    for (int mi = 0; mi < 2; mi++)
        #pragma unroll
        for (int ni = 0; ni < 4; ni++)
            #pragma unroll
            for (int j = 0; j < 4; j++)
                C[(size_t)(m0 + wr + mi * 16 + lg * 4 + j) * HID
                  + n0 + wc + ni * 16 + lc] = acc[mi][ni][j];
}

// ---------------------------------------------------------------------------
// K3: causal GQA flash attention — 8-WAVE blocks over 128 q-rows sharing the
// same 64-key K/V tiles (staging per wave halves; LDS 51200 B -> still
// 3 blocks/CU but 24 waves/CU = 2x TLP). Iteration body identical to the
// stable r12 structure: vmcnt(2) (K) before QK, vmcnt(0)+barrier before PV.
// Split-K <=16 k-blocks via 24-entry LPT table; grid 384 x 512 threads.
// ---------------------------------------------------------------------------
__global__ __launch_bounds__(512, 6) void attn_kernel(
    const unsigned short* __restrict__ q,   // bf16, pre-scaled by QSCL
    const unsigned short* __restrict__ k,
    const unsigned short* __restrict__ vt,  // bf16 [KVDIM][T]
    unsigned short* __restrict__ o,
    float* __restrict__ pO,                 // fp32 [256][128][128]
    float* __restrict__ pML)                // fp32 [256][2][128]
{
    __shared__ alignas(16) unsigned short Ks[64 * 128];   // 16 KB
    __shared__ alignas(16) unsigned short Vs[128 * 64];   // 16 KB
    __shared__ alignas(16) unsigned short P[8][16][72];   // 18 KB

    const int tid  = threadIdx.x;
    const int lane = tid & 63;
    const int w    = tid >> 6;               // 0..7
    const int lg   = lane >> 4, lc = lane & 15;
    const int b    = blockIdx.x;
    const int h    = b & 15;
    const int e    = b >> 4;                 // 0..23 schedule entry

    const int tau    = S2_TAU[e];            // 128-row tile index 0..15
    const int kstart = S2_CST[e];            // in 64-key blocks
    const int kcnt   = S2_CNT[e];
    const int slt    = S2_SLT[e];            // 255 = direct write

    const int q0   = tau * 128 + w * 16;
    const int hk   = h >> 3;
    const int xr   = (lc & 7) << 4;

    const int krow_l = (lane >> 4);
    const int kgS    = (lane & 15);
    const int vrow_l = (lane >> 3);
    const int vgS    = (lane & 7);

    u16x8 qf[4];
    #pragma unroll
    for (int dc = 0; dc < 4; dc++)
        qf[dc] = *reinterpret_cast<const u16x8*>(
            &q[(size_t)(q0 + lc) * QDIM + h * HD + dc * 32 + lg * 8]);

    float mrow = -1e30f, ell = 0.f;          // log2 units
    f32x4 oacc[8] = {};

    auto stage = [&](int kb) {
        #pragma unroll
        for (int ci = 0; ci < 2; ci++) {     // K first (vmcnt FIFO): 2 chunks/wave
            const int chunk = w * 2 + ci;    // 0..15, 4 rows each
            const int row   = chunk * 4 + krow_l;
            const int gSk   = kgS ^ (row & 7);
            const unsigned short* gp =
                &k[(size_t)(kb + row) * KVDIM + hk * HD + gSk * 8];
            __builtin_amdgcn_global_load_lds(
                (const __attribute__((address_space(1))) void*)gp,
                (__attribute__((address_space(3))) void*)(&Ks[chunk * 512]),
                16, 0, 0);
        }
        #pragma unroll
        for (int ci = 0; ci < 2; ci++) {     // then V: 2 chunks/wave
            const int chunk = w * 2 + ci;    // 0..15, 8 d-rows each
            const int dr    = chunk * 8 + vrow_l;
            const int gSv   = vgS ^ (dr & 7);
            const unsigned short* gp =
                &vt[(size_t)(hk * HD + dr) * T_TOK + kb + gSv * 8];
            __builtin_amdgcn_global_load_lds(
                (const __attribute__((address_space(1))) void*)gp,
                (__attribute__((address_space(3))) void*)(&Vs[chunk * 512]),
                16, 0, 0);
        }
    };

    for (int it = 0; it < kcnt; ++it) {
        const int kb = (kstart + it) * 64;
        stage(kb);
        asm volatile("s_waitcnt vmcnt(2)" ::: "memory");   // K landed (this wave)
        __syncthreads();                                   // K landed (all waves)

        const char* KsB = (const char*)Ks;
        const char* VsB = (const char*)Vs;

        float sc[4][4];
        const bool dia = (kb + 63 > q0);     // wave-uniform
        #pragma unroll
        for (int c4 = 0; c4 < 4; c4++) {
            const int row = c4 * 16 + lc;
            f32x4 s = {0.f, 0.f, 0.f, 0.f};
            #pragma unroll
            for (int dc = 0; dc < 4; dc++) {
                u16x8 kf = *reinterpret_cast<const u16x8*>(
                    KsB + row * 256 + ((dc * 64 + lg * 16) ^ xr));
                s = mfma16(kf, qf[dc], s);   // SWAPPED: A=K, B=Q
            }
            if (dia) {
                #pragma unroll
                for (int j = 0; j < 4; j++) {
                    const int kpos = kb + c4 * 16 + lg * 4 + j;
                    sc[c4][j] = (kpos <= q0 + lc) ? s[j] : -1e30f;
                }
            } else {
                #pragma unroll
                for (int j = 0; j < 4; j++) sc[c4][j] = s[j];
            }
        }

        float t01 = fmaxf(fmaxf(sc[0][0], sc[0][1]), fmaxf(sc[0][2], sc[0][3]));
        float t23 = fmaxf(fmaxf(sc[1][0], sc[1][1]), fmaxf(sc[1][2], sc[1][3]));
        float t45 = fmaxf(fmaxf(sc[2][0], sc[2][1]), fmaxf(sc[2][2], sc[2][3]));
        float t67 = fmaxf(fmaxf(sc[3][0], sc[3][1]), fmaxf(sc[3][2], sc[3][3]));
        float tmx = fmaxf(fmaxf(t01, t23), fmaxf(t45, t67));
        tmx = fmaxf(tmx, __shfl_xor(tmx, 16));
        tmx = fmaxf(tmx, __shfl_xor(tmx, 32));

        float mn;
        if (__all(tmx <= mrow + DEFER_THR)) {   // defer-max (T13)
            mn = mrow;
        } else {
            mn = fmaxf(mrow, tmx);
            float alpha = __builtin_amdgcn_exp2f(mrow - mn);
            mrow = mn;
            ell *= alpha;
            float aj[4];
            #pragma unroll
            for (int j = 0; j < 4; j++)
                aj[j] = __shfl(alpha, lg * 4 + j);
            #pragma unroll
            for (int d8 = 0; d8 < 8; d8++)
                #pragma unroll
                for (int j = 0; j < 4; j++)
                    oacc[d8][j] *= aj[j];
        }

        float rs = 0.f;
        #pragma unroll
        for (int c4 = 0; c4 < 4; c4++) {
            float p0 = __builtin_amdgcn_exp2f(sc[c4][0] - mn);
            float p1 = __builtin_amdgcn_exp2f(sc[c4][1] - mn);
            float p2 = __builtin_amdgcn_exp2f(sc[c4][2] - mn);
            float p3 = __builtin_amdgcn_exp2f(sc[c4][3] - mn);
            rs += (p0 + p1) + (p2 + p3);
            ushort4 pk;
            pk.x = f2bf(p0); pk.y = f2bf(p1); pk.z = f2bf(p2); pk.w = f2bf(p3);
            *reinterpret_cast<ushort4*>(&P[w][lc][c4 * 16 + lg * 4]) = pk;
        }
        rs += __shfl_xor(rs, 16);
        rs += __shfl_xor(rs, 32);
        ell += rs;

        // V landed on all waves before PV reads Vs
        asm volatile("s_waitcnt vmcnt(0) lgkmcnt(0)" ::: "memory");
        __builtin_amdgcn_sched_barrier(0);
        __syncthreads();

        u16x8 pf0 = *reinterpret_cast<const u16x8*>(&P[w][lc][lg * 8]);
        u16x8 pf1 = *reinterpret_cast<const u16x8*>(&P[w][lc][32 + lg * 8]);

        #pragma unroll
        for (int d8 = 0; d8 < 8; d8++) {
            const int drow = d8 * 16 + lc;
            u16x8 vf0 = *reinterpret_cast<const u16x8*>(
                VsB + drow * 128 + ((lg * 16) ^ xr));
            u16x8 vf1 = *reinterpret_cast<const u16x8*>(
                VsB + drow * 128 + ((lg * 16 + 64) ^ xr));
            oacc[d8] = mfma16(pf0, vf0, oacc[d8]);
            oacc[d8] = mfma16(pf1, vf1, oacc[d8]);
        }
        if (it + 1 < kcnt) __syncthreads();   // done reading Ks/Vs before restage
    }

    if (slt == 255) {
        float ej[4];
        #pragma unroll
        for (int j = 0; j < 4; j++)
            ej[j] = __shfl(ell, lg * 4 + j);
        #pragma unroll
        for (int d8 = 0; d8 < 8; d8++)
            #pragma unroll
            for (int j = 0; j < 4; j++) {
                float val = oacc[d8][j] / ej[j];
                o[(size_t)(q0 + lg * 4 + j) * QDIM + h * HD + d8 * 16 + lc] = f2bf(val);
            }
    } else {
        const int slot = h * 16 + slt;                    // 0..255
        float* po = pO + (size_t)slot * 16384;            // [128][128]
        #pragma unroll
        for (int d8 = 0; d8 < 8; d8++)
            #pragma unroll
            for (int j = 0; j < 4; j++)
                po[(w * 16 + lg * 4 + j) * 128 + d8 * 16 + lc] = oacc[d8][j];
        if (lg == 0) {
            pML[slot * 256 + w * 16 + lc]       = mrow;
            pML[slot * 256 + 128 + w * 16 + lc] = ell;
        }
    }
}

// ---------------------------------------------------------------------------
// K3b: combine two split-K partials (128-row tiles) -> bf16 output.
// Grid (8, 16): tau = 8 + bx. 256 threads: 2 threads/row x 64 cols.
// ---------------------------------------------------------------------------
__global__ __launch_bounds__(256) void attn_combine(
    const float* __restrict__ pO,
    const float* __restrict__ pML,
    unsigned short* __restrict__ o)
{
    const int tau = 8 + blockIdx.x;          // 8..15
    const int h   = blockIdx.y;
    const int s0  = h * 16 + (tau - 8) * 2, s1 = s0 + 1;

    const int tid = threadIdx.x;
    const int r   = tid >> 1;                // 0..127
    const int cg  = (tid & 1) * 64;          // 0 or 64

    const float m1 = pML[s0 * 256 + r],       m2 = pML[s1 * 256 + r];
    const float l1 = pML[s0 * 256 + 128 + r], l2 = pML[s1 * 256 + 128 + r];
    const float M  = fmaxf(m1, m2);
    const float w1 = __builtin_amdgcn_exp2f(m1 - M);
    const float w2 = __builtin_amdgcn_exp2f(m2 - M);
    const float rn = 1.0f / (w1 * l1 + w2 * l2);

    const float* o1 = pO + (size_t)s0 * 16384 + r * 128 + cg;
    const float* o2 = pO + (size_t)s1 * 16384 + r * 128 + cg;
    unsigned short* dst = o + (size_t)(tau * 128 + r) * QDIM + h * HD + cg;

    #pragma unroll
    for (int i = 0; i < 16; i++) {
        float4 a = *reinterpret_cast<const float4*>(o1 + i * 4);
        float4 c = *reinterpret_cast<const float4*>(o2 + i * 4);
        ushort4 pk;
        pk.x = f2bf((w1 * a.x + w2 * c.x) * rn);
        pk.y = f2bf((w1 * a.y + w2 * c.y) * rn);
        pk.z = f2bf((w1 * a.z + w2 * c.z) * rn);
        pk.w = f2bf((w1 * a.w + w2 * c.w) * rn);
        *reinterpret_cast<ushort4*>(dst + i * 4) = pk;
    }
}

// ---------------------------------------------------------------------------
extern "C" void kernel_launch(void* const* d_in, const int* in_sizes, int n_in,
                              void* d_out, int out_size, void* d_ws, size_t ws_size,
                              hipStream_t stream) {
    const float* hidden    = (const float*)d_in[0];
    const int*   positions = (const int*)d_in[1];
    const float* Wq        = (const float*)d_in[2];
    const float* Wk        = (const float*)d_in[3];
    const float* Wv        = (const float*)d_in[4];
    const float* Wo        = (const float*)d_in[5];
    float*       out       = (float*)d_out;

    char* ws = (char*)d_ws;
    // [0, 16777216)        : pO   256 slots x 128x128 fp32
    // [16777216, 17039360) : pML  256 slots x 2x128 fp32
    // [17039360, 18087936) : ctab fp32 [T][128] cos|sin
    float* pO   = (float*)(ws);
    float* pML  = (float*)(ws + 16777216);
    float* ctab = (float*)(ws + 17039360);
    unsigned short* qr  = (unsigned short*)(ws + 20971520); // 8388608 B
    unsigned short* kr  = (unsigned short*)(ws + 29360128); // 1048576 B
    unsigned short* vt  = (unsigned short*)(ws + 30408704); // 1048576 B
    unsigned short* att = (unsigned short*)(ws + 31457280); // 8388608 B
    unsigned short* hb  = (unsigned short*)(ws + 39845888); // 8388608 B
    unsigned short* Wf  = (unsigned short*)(ws + 48234496); // 10485760 B
    unsigned short* Wob = (unsigned short*)(ws + 58720256); // 8388608 B

    pack_bf16_all<<<7168, 256, 0, stream>>>(hidden, Wq, Wk, Wv, Wo, positions,
                                            hb, Wf, Wob, ctab);
    qkv_gemm_fused<<<640, 256, 0, stream>>>(hb, Wf, ctab, qr, kr, vt);
    attn_kernel<<<NH * 24, 512, 0, stream>>>(qr, kr, vt, att, pO, pML);
    attn_combine<<<dim3(8, 16), 256, 0, stream>>>(pO, pML, att);
    gemm_out<<<512, 256, 0, stream>>>(att, Wob, out);
}

// Round 19
// 125.534 us; speedup vs baseline: 1.4332x; 1.4332x over previous
//
#include <hip/hip_runtime.h>

#define T_TOK 2048
#define HID   2048
#define NH    16
#define NKV   2
#define HD    128
#define QDIM  (NH * HD)                 // 2048
#define KVDIM (NKV * HD)                // 256
#define QKVDIM (QDIM + 2 * KVDIM)       // 2560

typedef float          f32x4  __attribute__((ext_vector_type(4)));
typedef unsigned short u16x8  __attribute__((ext_vector_type(8)));
typedef __bf16         bf16x8 __attribute__((ext_vector_type(8)));

__device__ __forceinline__ unsigned short f2bf(float f) {
    __bf16 h = (__bf16)f;
    return __builtin_bit_cast(unsigned short, h);
}

__device__ __forceinline__ f32x4 mfma16(u16x8 a, u16x8 b, f32x4 c) {
    return __builtin_amdgcn_mfma_f32_16x16x32_bf16(
        __builtin_bit_cast(bf16x8, a), __builtin_bit_cast(bf16x8, b), c, 0, 0, 0);
}

#define QSCL 0.12751743f        // 128^-0.5 * log2(e)
#define DEFER_THR 11.5416f      // defer-max threshold (log2 units)

// ---------------------------------------------------------------------------
// K0: fp32->bf16 packs (blocks 0..6655) + RoPE cos/sin table (6656..7167).
// ---------------------------------------------------------------------------
__global__ __launch_bounds__(256) void pack_bf16_all(
    const float* __restrict__ hidden, const float* __restrict__ Wq,
    const float* __restrict__ Wk, const float* __restrict__ Wv,
    const float* __restrict__ Wo, const int* __restrict__ positions,
    unsigned short* __restrict__ hb, unsigned short* __restrict__ Wf,
    unsigned short* __restrict__ Wob, float* __restrict__ ctab)
{
    const int b = blockIdx.x;
    if (b >= 6656) {
        const int bb = b - 6656;                 // 0..511
        const int t  = bb * 4 + (threadIdx.x >> 6);
        const int j  = threadIdx.x & 63;
        float invf = expf(-(float)j * 0.14391156831212787f);  // 10000^(-j/64)
        float f = (float)positions[t] * invf;
        ctab[(size_t)t * 128 + j]      = cosf(f);
        ctab[(size_t)t * 128 + 64 + j] = sinf(f);
        return;
    }
    const float* src; unsigned short* dst; size_t off;
    if      (b < 2048) { src = hidden; dst = hb;            off = (size_t)b * 2048; }
    else if (b < 4096) { src = Wq;     dst = Wf;            off = (size_t)(b - 2048) * 2048; }
    else if (b < 4352) { src = Wk;     dst = Wf + 4194304;  off = (size_t)(b - 4096) * 2048; }
    else if (b < 4608) { src = Wv;     dst = Wf + 4718592;  off = (size_t)(b - 4352) * 2048; }
    else               { src = Wo;     dst = Wob;           off = (size_t)(b - 4608) * 2048; }

    const size_t i = off + threadIdx.x * 8;
    float4 f0 = *reinterpret_cast<const float4*>(src + i);
    float4 f1 = *reinterpret_cast<const float4*>(src + i + 4);
    u16x8 o;
    o[0]=f2bf(f0.x); o[1]=f2bf(f0.y); o[2]=f2bf(f0.z); o[3]=f2bf(f0.w);
    o[4]=f2bf(f1.x); o[5]=f2bf(f1.y); o[6]=f2bf(f1.z); o[7]=f2bf(f1.w);
    *reinterpret_cast<u16x8*>(dst + i) = o;
}

// ---------------------------------------------------------------------------
// K1a: fused QKV GEMM. 64x128 tile, BK=64, 2-deep global_load_lds +
// counted vmcnt(6), XCD rectangle remap (8m x 10n per XCD).
// Epilogue fuses RoPE (q pre-scaled by QSCL) and V-transpose.
// ---------------------------------------------------------------------------
__global__ __launch_bounds__(256) void qkv_gemm_fused(
    const unsigned short* __restrict__ A,   // hb  bf16 [2048][2048]
    const unsigned short* __restrict__ B,   // Wf  bf16 [2560][2048]
    const float* __restrict__ ctab,         // [T][128] cos|sin
    unsigned short* __restrict__ qr,        // bf16 [T][QDIM], pre-scaled
    unsigned short* __restrict__ kr,        // bf16 [T][KVDIM]
    unsigned short* __restrict__ vt)        // bf16 [KVDIM][T]
{
    __shared__ alignas(16) char smem[49152];
    unsigned short* AsBase = (unsigned short*)smem;           // [2][4096]
    unsigned short* BsBase = (unsigned short*)(smem + 16384); // [2][8192]

    const int tid  = threadIdx.x;
    const int lane = tid & 63;
    const int w    = tid >> 6;
    const int lg   = lane >> 4, lc = lane & 15;

    const int x  = blockIdx.x & 7;
    const int l  = blockIdx.x >> 3;          // 0..79
    const int mt = (x >> 1) * 8 + l / 10;    // 0..31
    const int nt = (x & 1) * 10 + l % 10;    // 0..19
    const int m0 = mt * 64, n0 = nt * 128;

    const int rowL = lane >> 3;
    const int gS   = (lane & 7) ^ rowL;
    const int wr   = (w >> 1) * 32, wc = (w & 1) * 64;

    f32x4 acc[2][4] = {};

    auto stage = [&](int buf, int kb) {
        #pragma unroll
        for (int ci = 0; ci < 2; ci++) {
            const int chunk = w * 2 + ci;
            const int row   = chunk * 8 + rowL;
            const unsigned short* gpA = &A[(size_t)(m0 + row) * HID + kb + gS * 8];
            __builtin_amdgcn_global_load_lds(
                (const __attribute__((address_space(1))) void*)gpA,
                (__attribute__((address_space(3))) void*)(&AsBase[buf * 4096 + chunk * 512]),
                16, 0, 0);
        }
        #pragma unroll
        for (int ci = 0; ci < 4; ci++) {
            const int chunk = w * 4 + ci;
            const int row   = chunk * 8 + rowL;
            const unsigned short* gpB = &B[(size_t)(n0 + row) * HID + kb + gS * 8];
            __builtin_amdgcn_global_load_lds(
                (const __attribute__((address_space(1))) void*)gpB,
                (__attribute__((address_space(3))) void*)(&BsBase[buf * 8192 + chunk * 512]),
                16, 0, 0);
        }
    };

    stage(0, 0);
    const int nk = HID >> 6;
    for (int t = 0; t < nk; ++t) {
        if (t + 1 < nk) {
            stage((t + 1) & 1, (t + 1) * 64);
            asm volatile("s_waitcnt vmcnt(6)" ::: "memory");
        } else {
            asm volatile("s_waitcnt vmcnt(0)" ::: "memory");
        }
        __syncthreads();

        const unsigned short* As_ = &AsBase[(t & 1) * 4096];
        const unsigned short* Bs_ = &BsBase[(t & 1) * 8192];
        #pragma unroll
        for (int kk = 0; kk < 2; kk++) {
            u16x8 af[2], bf[4];
            const int g = (kk * 4 + lg) ^ (lc & 7);
            #pragma unroll
            for (int mi = 0; mi < 2; mi++) {
                const int r = wr + mi * 16 + lc;
                af[mi] = *reinterpret_cast<const u16x8*>(&As_[r * 64 + g * 8]);
            }
            #pragma unroll
            for (int ni = 0; ni < 4; ni++) {
                const int r = wc + ni * 16 + lc;
                bf[ni] = *reinterpret_cast<const u16x8*>(&Bs_[r * 64 + g * 8]);
            }
            #pragma unroll
            for (int mi = 0; mi < 2; mi++)
                #pragma unroll
                for (int ni = 0; ni < 4; ni++)
                    acc[mi][ni] = mfma16(af[mi], bf[ni], acc[mi][ni]);
        }
        __syncthreads();
    }

    // ------------------ fused epilogue ------------------
    if (n0 < QDIM + KVDIM) {
        float* Ep = (float*)smem;                        // 64 x 132 f32
        #pragma unroll
        for (int mi = 0; mi < 2; mi++)
            #pragma unroll
            for (int ni = 0; ni < 4; ni++)
                #pragma unroll
                for (int j = 0; j < 4; j++)
                    Ep[(wr + mi * 16 + lg * 4 + j) * 132 + wc + ni * 16 + lc]
                        = acc[mi][ni][j];
        __syncthreads();

        const bool isq = (n0 < QDIM);
        const float scl = isq ? QSCL : 1.0f;
        unsigned short* dst  = isq ? qr : kr;
        const int rowstride  = isq ? QDIM : KVDIM;
        const int colbase    = isq ? n0 : (n0 - QDIM);

        const int r  = tid >> 2;
        const int jb = (tid & 3) * 16;
        const float* ct = ctab + (size_t)(m0 + r) * 128;
        unsigned short* drow = dst + (size_t)(m0 + r) * rowstride + colbase;
        #pragma unroll
        for (int g = 0; g < 4; g++) {
            ushort4 p1, p2;
            #pragma unroll
            for (int e = 0; e < 4; e++) {
                const int j = jb + g * 4 + e;
                float x1 = Ep[r * 132 + j];
                float x2 = Ep[r * 132 + j + 64];
                float c = ct[j], s = ct[64 + j];
                ((unsigned short*)&p1)[e] = f2bf((x1 * c - x2 * s) * scl);
                ((unsigned short*)&p2)[e] = f2bf((x2 * c + x1 * s) * scl);
            }
            *reinterpret_cast<ushort4*>(drow + jb + g * 4)      = p1;
            *reinterpret_cast<ushort4*>(drow + jb + g * 4 + 64) = p2;
        }
    } else {
        #pragma unroll
        for (int mi = 0; mi < 2; mi++)
            #pragma unroll
            for (int ni = 0; ni < 4; ni++) {
                const int d   = (n0 - QDIM - KVDIM) + wc + ni * 16 + lc;
                const int t0r = m0 + wr + mi * 16 + lg * 4;
                ushort4 pk;
                pk.x = f2bf(acc[mi][ni][0]);
                pk.y = f2bf(acc[mi][ni][1]);
                pk.z = f2bf(acc[mi][ni][2]);
                pk.w = f2bf(acc[mi][ni][3]);
                *reinterpret_cast<ushort4*>(&vt[(size_t)d * T_TOK + t0r]) = pk;
            }
    }
}

// ---------------------------------------------------------------------------
// K1b: out-proj GEMM. 64x128 tile, BK=64, 3-deep pipelined global_load_lds
// (vmcnt(12)), XCD rectangle remap (8m x 8n per XCD).
// ---------------------------------------------------------------------------
__global__ __launch_bounds__(256) void gemm_out(
    const unsigned short* __restrict__ A,   // att bf16 [T][QDIM]
    const unsigned short* __restrict__ B,   // Wob bf16 [HID][QDIM]
    float* __restrict__ C)                  // fp32 [T][HID]
{
    __shared__ alignas(16) unsigned short As[3][64 * 64];
    __shared__ alignas(16) unsigned short Bs[3][128 * 64];

    const int tid  = threadIdx.x;
    const int lane = tid & 63;
    const int w    = tid >> 6;
    const int lg   = lane >> 4, lc = lane & 15;

    const int x  = blockIdx.x & 7;
    const int l  = blockIdx.x >> 3;          // 0..63
    const int mt = (x >> 1) * 8 + (l >> 3);  // 0..31
    const int nt = (x & 1) * 8 + (l & 7);    // 0..15
    const int m0 = mt * 64, n0 = nt * 128;

    const int rowL = lane >> 3;
    const int gS   = (lane & 7) ^ rowL;
    const int wr   = (w >> 1) * 32, wc = (w & 1) * 64;

    f32x4 acc[2][4] = {};

    auto stage = [&](int buf, int kb) {
        #pragma unroll
        for (int ci = 0; ci < 2; ci++) {
            const int chunk = w * 2 + ci;
            const int row   = chunk * 8 + rowL;
            const unsigned short* gpA = &A[(size_t)(m0 + row) * QDIM + kb + gS * 8];
            __builtin_amdgcn_global_load_lds(
                (const __attribute__((address_space(1))) void*)gpA,
                (__attribute__((address_space(3))) void*)(&As[buf][chunk * 512]),
                16, 0, 0);
        }
        #pragma unroll
        for (int ci = 0; ci < 4; ci++) {
            const int chunk = w * 4 + ci;
            const int row   = chunk * 8 + rowL;
            const unsigned short* gpB = &B[(size_t)(n0 + row) * QDIM + kb + gS * 8];
            __builtin_amdgcn_global_load_lds(
                (const __attribute__((address_space(1))) void*)gpB,
                (__attribute__((address_space(3))) void*)(&Bs[buf][chunk * 512]),
                16, 0, 0);
        }
    };

    stage(0, 0);
    stage(1, 64);
    const int nk = QDIM >> 6;                // 32
    int buf = 0;
    for (int t = 0; t < nk; ++t) {
        if (t + 2 < nk) {
            stage((t + 2) % 3, (t + 2) * 64);
            asm volatile("s_waitcnt vmcnt(12)" ::: "memory");
        } else if (t + 1 < nk) {
            asm volatile("s_waitcnt vmcnt(6)" ::: "memory");
        } else {
            asm volatile("s_waitcnt vmcnt(0)" ::: "memory");
        }
        __syncthreads();

        const unsigned short* As_ = As[buf];
        const unsigned short* Bs_ = Bs[buf];
        #pragma unroll
        for (int kk = 0; kk < 2; kk++) {
            u16x8 af[2], bf[4];
            const int g = (kk * 4 + lg) ^ (lc & 7);
            #pragma unroll
            for (int mi = 0; mi < 2; mi++) {
                const int r = wr + mi * 16 + lc;
                af[mi] = *reinterpret_cast<const u16x8*>(&As_[r * 64 + g * 8]);
            }
            #pragma unroll
            for (int ni = 0; ni < 4; ni++) {
                const int r = wc + ni * 16 + lc;
                bf[ni] = *reinterpret_cast<const u16x8*>(&Bs_[r * 64 + g * 8]);
            }
            #pragma unroll
            for (int mi = 0; mi < 2; mi++)
                #pragma unroll
                for (int ni = 0; ni < 4; ni++)
                    acc[mi][ni] = mfma16(af[mi], bf[ni], acc[mi][ni]);
        }
        __syncthreads();
        buf = (buf == 2) ? 0 : buf + 1;
    }

    #pragma unroll
    for (int mi = 0; mi < 2; mi++)
        #pragma unroll
        for (int ni = 0; ni < 4; ni++)
            #pragma unroll
            for (int j = 0; j < 4; j++)
                C[(size_t)(m0 + wr + mi * 16 + lg * 4 + j) * HID
                  + n0 + wc + ni * 16 + lc] = acc[mi][ni][j];
}

// ---------------------------------------------------------------------------
// K3: causal GQA flash attention (stable 43.5 µs config). Split-K <=16
// k-blocks (768 blocks, LPT), single-buffered K/V via global_load_lds;
// vmcnt(4) before QK, vmcnt(0)+barrier before PV.
// ---------------------------------------------------------------------------
__global__ __launch_bounds__(256) void attn_kernel(
    const unsigned short* __restrict__ q,   // bf16, pre-scaled by QSCL
    const unsigned short* __restrict__ k,
    const unsigned short* __restrict__ vt,  // bf16 [KVDIM][T]
    unsigned short* __restrict__ o,
    float* __restrict__ pO,                 // fp32 [512][64][128]
    float* __restrict__ pML)                // fp32 [512][2][64]
{
    __shared__ alignas(16) unsigned short Ks[64 * 128];
    __shared__ alignas(16) unsigned short Vs[128 * 64];
    __shared__ alignas(16) unsigned short P[4][16][72];

    const int tid  = threadIdx.x;
    const int lane = tid & 63;
    const int w    = tid >> 6;
    const int lg   = lane >> 4, lc = lane & 15;
    const int b    = blockIdx.x;
    const int h    = b & 15;
    const int idx  = b >> 4;                 // 0..47, LPT order

    int tau, c0;
    if (idx <= 16)      { tau = 15 + idx; c0 = 0; }
    else if (idx == 17) { tau = 31;       c0 = 1; }
    else {
        int j = idx - 18, kk = 15 - (j >> 1);
        if ((j & 1) == 0) { tau = kk - 1;  c0 = 0; }
        else              { tau = kk + 15; c0 = 1; }
    }
    const int kstart = c0 << 4;              // in 64-key blocks
    const int kcnt   = min(16, tau + 1 - kstart);

    const int q0   = tau * 64 + w * 16;
    const int hk   = h >> 3;
    const int xr   = (lc & 7) << 4;

    const int krow_l = (lane >> 4);
    const int kgS    = (lane & 15);
    const int vrow_l = (lane >> 3);
    const int vgS    = (lane & 7);

    u16x8 qf[4];
    #pragma unroll
    for (int dc = 0; dc < 4; dc++)
        qf[dc] = *reinterpret_cast<const u16x8*>(
            &q[(size_t)(q0 + lc) * QDIM + h * HD + dc * 32 + lg * 8]);

    float mrow = -1e30f, ell = 0.f;          // log2 units
    f32x4 oacc[8] = {};

    auto stage = [&](int kb) {
        #pragma unroll
        for (int ci = 0; ci < 4; ci++) {     // K first (vmcnt FIFO)
            const int chunk = w * 4 + ci;
            const int row   = chunk * 4 + krow_l;
            const int gSk   = kgS ^ (row & 7);
            const unsigned short* gp =
                &k[(size_t)(kb + row) * KVDIM + hk * HD + gSk * 8];
            __builtin_amdgcn_global_load_lds(
                (const __attribute__((address_space(1))) void*)gp,
                (__attribute__((address_space(3))) void*)(&Ks[chunk * 512]),
                16, 0, 0);
        }
        #pragma unroll
        for (int ci = 0; ci < 4; ci++) {     // then V
            const int chunk = w * 4 + ci;
            const int dr    = chunk * 8 + vrow_l;
            const int gSv   = vgS ^ (dr & 7);
            const unsigned short* gp =
                &vt[(size_t)(hk * HD + dr) * T_TOK + kb + gSv * 8];
            __builtin_amdgcn_global_load_lds(
                (const __attribute__((address_space(1))) void*)gp,
                (__attribute__((address_space(3))) void*)(&Vs[chunk * 512]),
                16, 0, 0);
        }
    };

    for (int it = 0; it < kcnt; ++it) {
        const int kb = (kstart + it) * 64;
        stage(kb);
        asm volatile("s_waitcnt vmcnt(4)" ::: "memory");   // K landed (this wave)
        __syncthreads();                                   // K landed (all waves)

        const char* KsB = (const char*)Ks;
        const char* VsB = (const char*)Vs;

        float sc[4][4];
        const bool dia = (kb + 63 > q0);
        #pragma unroll
        for (int c4 = 0; c4 < 4; c4++) {
            const int row = c4 * 16 + lc;
            f32x4 s = {0.f, 0.f, 0.f, 0.f};
            #pragma unroll
            for (int dc = 0; dc < 4; dc++) {
                u16x8 kf = *reinterpret_cast<const u16x8*>(
                    KsB + row * 256 + ((dc * 64 + lg * 16) ^ xr));
                s = mfma16(kf, qf[dc], s);   // SWAPPED: A=K, B=Q
            }
            if (dia) {
                #pragma unroll
                for (int j = 0; j < 4; j++) {
                    const int kpos = kb + c4 * 16 + lg * 4 + j;
                    sc[c4][j] = (kpos <= q0 + lc) ? s[j] : -1e30f;
                }
            } else {
                #pragma unroll
                for (int j = 0; j < 4; j++) sc[c4][j] = s[j];
            }
        }

        float t01 = fmaxf(fmaxf(sc[0][0], sc[0][1]), fmaxf(sc[0][2], sc[0][3]));
        float t23 = fmaxf(fmaxf(sc[1][0], sc[1][1]), fmaxf(sc[1][2], sc[1][3]));
        float t45 = fmaxf(fmaxf(sc[2][0], sc[2][1]), fmaxf(sc[2][2], sc[2][3]));
        float t67 = fmaxf(fmaxf(sc[3][0], sc[3][1]), fmaxf(sc[3][2], sc[3][3]));
        float tmx = fmaxf(fmaxf(t01, t23), fmaxf(t45, t67));
        tmx = fmaxf(tmx, __shfl_xor(tmx, 16));
        tmx = fmaxf(tmx, __shfl_xor(tmx, 32));

        float mn;
        if (__all(tmx <= mrow + DEFER_THR)) {   // defer-max (T13)
            mn = mrow;
        } else {
            mn = fmaxf(mrow, tmx);
            float alpha = __builtin_amdgcn_exp2f(mrow - mn);
            mrow = mn;
            ell *= alpha;
            float aj[4];
            #pragma unroll
            for (int j = 0; j < 4; j++)
                aj[j] = __shfl(alpha, lg * 4 + j);
            #pragma unroll
            for (int d8 = 0; d8 < 8; d8++)
                #pragma unroll
                for (int j = 0; j < 4; j++)
                    oacc[d8][j] *= aj[j];
        }

        float rs = 0.f;
        #pragma unroll
        for (int c4 = 0; c4 < 4; c4++) {
            float p0 = __builtin_amdgcn_exp2f(sc[c4][0] - mn);
            float p1 = __builtin_amdgcn_exp2f(sc[c4][1] - mn);
            float p2 = __builtin_amdgcn_exp2f(sc[c4][2] - mn);
            float p3 = __builtin_amdgcn_exp2f(sc[c4][3] - mn);
            rs += (p0 + p1) + (p2 + p3);
            ushort4 pk;
            pk.x = f2bf(p0); pk.y = f2bf(p1); pk.z = f2bf(p2); pk.w = f2bf(p3);
            *reinterpret_cast<ushort4*>(&P[w][lc][c4 * 16 + lg * 4]) = pk;
        }
        rs += __shfl_xor(rs, 16);
        rs += __shfl_xor(rs, 32);
        ell += rs;

        // V landed on all waves before PV reads Vs
        asm volatile("s_waitcnt vmcnt(0) lgkmcnt(0)" ::: "memory");
        __builtin_amdgcn_sched_barrier(0);
        __syncthreads();

        u16x8 pf0 = *reinterpret_cast<const u16x8*>(&P[w][lc][lg * 8]);
        u16x8 pf1 = *reinterpret_cast<const u16x8*>(&P[w][lc][32 + lg * 8]);

        #pragma unroll
        for (int d8 = 0; d8 < 8; d8++) {
            const int drow = d8 * 16 + lc;
            u16x8 vf0 = *reinterpret_cast<const u16x8*>(
                VsB + drow * 128 + ((lg * 16) ^ xr));
            u16x8 vf1 = *reinterpret_cast<const u16x8*>(
                VsB + drow * 128 + ((lg * 16 + 64) ^ xr));
            oacc[d8] = mfma16(pf0, vf0, oacc[d8]);
            oacc[d8] = mfma16(pf1, vf1, oacc[d8]);
        }
        if (it + 1 < kcnt) __syncthreads();   // done reading Ks/Vs before restage
    }

    if (tau < 16) {
        float ej[4];
        #pragma unroll
        for (int j = 0; j < 4; j++)
            ej[j] = __shfl(ell, lg * 4 + j);
        #pragma unroll
        for (int d8 = 0; d8 < 8; d8++)
            #pragma unroll
            for (int j = 0; j < 4; j++) {
                float val = oacc[d8][j] / ej[j];
                o[(size_t)(q0 + lg * 4 + j) * QDIM + h * HD + d8 * 16 + lc] = f2bf(val);
            }
    } else {
        const int s = (h * 16 + (tau - 16)) * 2 + c0;
        float* po = pO + (size_t)s * 8192;
        #pragma unroll
        for (int d8 = 0; d8 < 8; d8++)
            #pragma unroll
            for (int j = 0; j < 4; j++)
                po[(w * 16 + lg * 4 + j) * 128 + d8 * 16 + lc] = oacc[d8][j];
        if (lg == 0) {
            pML[s * 128 + w * 16 + lc]      = mrow;
            pML[s * 128 + 64 + w * 16 + lc] = ell;
        }
    }
}

// ---------------------------------------------------------------------------
// K3b: combine two split-K partials (m in log2 units) -> bf16 output.
// ---------------------------------------------------------------------------
__global__ __launch_bounds__(256) void attn_combine(
    const float* __restrict__ pO,
    const float* __restrict__ pML,
    unsigned short* __restrict__ o)
{
    const int b  = blockIdx.x;
    const int h  = b >> 4, ti = b & 15;
    const int tau = 16 + ti;
    const int s0 = (h * 16 + ti) * 2, s1 = s0 + 1;

    const int tid = threadIdx.x;
    const int r   = tid >> 2;
    const int cg  = (tid & 3) * 32;

    const float m1 = pML[s0 * 128 + r],      m2 = pML[s1 * 128 + r];
    const float l1 = pML[s0 * 128 + 64 + r], l2 = pML[s1 * 128 + 64 + r];
    const float M  = fmaxf(m1, m2);
    const float w1 = __builtin_amdgcn_exp2f(m1 - M);
    const float w2 = __builtin_amdgcn_exp2f(m2 - M);
    const float rn = 1.0f / (w1 * l1 + w2 * l2);

    const float* o1 = pO + (size_t)s0 * 8192 + r * 128 + cg;
    const float* o2 = pO + (size_t)s1 * 8192 + r * 128 + cg;
    unsigned short* dst = o + (size_t)(tau * 64 + r) * QDIM + h * HD + cg;

    #pragma unroll
    for (int i = 0; i < 8; i++) {
        float4 a = *reinterpret_cast<const float4*>(o1 + i * 4);
        float4 c = *reinterpret_cast<const float4*>(o2 + i * 4);
        ushort4 pk;
        pk.x = f2bf((w1 * a.x + w2 * c.x) * rn);
        pk.y = f2bf((w1 * a.y + w2 * c.y) * rn);
        pk.z = f2bf((w1 * a.z + w2 * c.z) * rn);
        pk.w = f2bf((w1 * a.w + w2 * c.w) * rn);
        *reinterpret_cast<ushort4*>(dst + i * 4) = pk;
    }
}

// ---------------------------------------------------------------------------
extern "C" void kernel_launch(void* const* d_in, const int* in_sizes, int n_in,
                              void* d_out, int out_size, void* d_ws, size_t ws_size,
                              hipStream_t stream) {
    const float* hidden    = (const float*)d_in[0];
    const int*   positions = (const int*)d_in[1];
    const float* Wq        = (const float*)d_in[2];
    const float* Wk        = (const float*)d_in[3];
    const float* Wv        = (const float*)d_in[4];
    const float* Wo        = (const float*)d_in[5];
    float*       out       = (float*)d_out;

    char* ws = (char*)d_ws;
    // [0, 16777216)        : pO   split-K partials (attn stage)
    // [16777216, 17039360) : pML
    // [17039360, 18087936) : ctab fp32 [T][128] cos|sin (pack -> qkv gemm)
    float* pO   = (float*)(ws);
    float* pML  = (float*)(ws + 16777216);
    float* ctab = (float*)(ws + 17039360);
    unsigned short* qr  = (unsigned short*)(ws + 20971520); // 8388608 B
    unsigned short* kr  = (unsigned short*)(ws + 29360128); // 1048576 B
    unsigned short* vt  = (unsigned short*)(ws + 30408704); // 1048576 B
    unsigned short* att = (unsigned short*)(ws + 31457280); // 8388608 B
    unsigned short* hb  = (unsigned short*)(ws + 39845888); // 8388608 B
    unsigned short* Wf  = (unsigned short*)(ws + 48234496); // 10485760 B
    unsigned short* Wob = (unsigned short*)(ws + 58720256); // 8388608 B

    pack_bf16_all<<<7168, 256, 0, stream>>>(hidden, Wq, Wk, Wv, Wo, positions,
                                            hb, Wf, Wob, ctab);
    qkv_gemm_fused<<<640, 256, 0, stream>>>(hb, Wf, ctab, qr, kr, vt);
    attn_kernel<<<NH * 48, 256, 0, stream>>>(qr, kr, vt, att, pO, pML);
    attn_combine<<<256, 256, 0, stream>>>(pO, pML, att);
    gemm_out<<<512, 256, 0, stream>>>(att, Wob, out);
}